// Round 2
// baseline (560.225 us; speedup 1.0000x reference)
//
#include <hip/hip_runtime.h>
#include <math.h>

#define F 64

typedef __attribute__((ext_vector_type(8))) short bf16x8;
typedef __attribute__((ext_vector_type(4))) float f32x4;

__device__ inline unsigned short f2bf(float f) {
  unsigned int u = __float_as_uint(f);
  u += 0x7fffu + ((u >> 16) & 1u);   // round-to-nearest-even
  return (unsigned short)(u >> 16);
}

// ---------------- prep: W fragment pack (block 0) + ndeg zero + out init ----------------
__global__ __launch_bounds__(256) void k_prep(const float* __restrict__ W1, const float* __restrict__ W2,
                                              uint4* __restrict__ wf, int* __restrict__ ndeg, int n,
                                              float* __restrict__ out, const float* __restrict__ bo, int ng) {
  int tid = threadIdx.x;
  if (blockIdx.x == 0) {
    // pack W1/W2 into MFMA B-fragment layout: wf[layer*512 + (c*2+kk)*64 + lane] = 8 bf16 (j=0..7)
    for (int i = tid; i < 1024; i += 256) {
      int layer = i >> 9, rem = i & 511;
      int cb = rem >> 6, lane = rem & 63;
      int c = cb >> 1, kk = cb & 1;
      int l15 = lane & 15, quad = lane >> 4;
      const float* W = layer ? W2 : W1;
      unsigned short p[8];
      #pragma unroll
      for (int j = 0; j < 8; j++) {
        int kd = kk * 32 + quad * 8 + j;
        p[j] = f2bf(W[kd * F + c * 16 + l15]);
      }
      wf[i] = *(const uint4*)p;
    }
  } else {
    int base = (blockIdx.x - 1) * 256 + tid;
    int stride = 255 * 256;
    for (int i = base; i < n; i += stride) ndeg[i] = 0;
    float b0 = bo[0];
    for (int i = base; i < ng; i += stride) out[i] = b0;
  }
}

// ---------------- pass 1: per-node in-degree count (fire-and-forget atomics) ----------------
__global__ __launch_bounds__(256) void k_count(const int* __restrict__ edst, int* __restrict__ ndeg,
                                               int e, int ch) {
  int k = blockIdx.x, tid = threadIdx.x;
  int beg = k * ch, end = min(e, beg + ch);
  int len = end - beg;
  if (len <= 0) return;
  int nv = len >> 2;  // beg is 16B-aligned (ch multiple of 4, E multiple of 4)
  for (int g = tid; g < nv; g += 256) {
    int4 d4 = *(const int4*)(edst + beg + (g << 2));
    atomicAdd(&ndeg[d4.x], 1);
    atomicAdd(&ndeg[d4.y], 1);
    atomicAdd(&ndeg[d4.z], 1);
    atomicAdd(&ndeg[d4.w], 1);
  }
  for (int i = beg + (nv << 2) + tid; i < end; i += 256) atomicAdd(&ndeg[edst[i]], 1);
}

// per-256-block exclusive scan; block totals to bsums
__global__ __launch_bounds__(256) void k_scan1(const int* __restrict__ counts, int* __restrict__ ppos,
                                               int* __restrict__ bsums, int n) {
  int tid = threadIdx.x, lane = tid & 63, wv = tid >> 6;
  int i = blockIdx.x * 256 + tid;
  int v = (i < n) ? counts[i] : 0;
  int x = v;
  #pragma unroll
  for (int o = 1; o <= 32; o <<= 1) { int y = __shfl_up(x, o); if (lane >= o) x += y; }
  __shared__ int wsum[4];
  if (lane == 63) wsum[wv] = x;
  __syncthreads();
  int add = 0;
  for (int w = 0; w < wv; w++) add += wsum[w];
  int incl = x + add;
  if (i < n) ppos[i] = incl - v;
  if (tid == 255) bsums[blockIdx.x] = incl;
}

// per-block: reduce prefix of bsums (redundantly, it's tiny) -> global offs + cur
__global__ __launch_bounds__(256) void k_init(const int* __restrict__ ppos, const int* __restrict__ bsums,
                                              int* __restrict__ offs, int* __restrict__ cur,
                                              int* __restrict__ ssrc, int n, int e) {
  __shared__ int rbuf[256];
  int tid = threadIdx.x, b = blockIdx.x;
  int acc = 0;
  for (int t = tid; t < b; t += 256) acc += bsums[t];
  rbuf[tid] = acc;
  __syncthreads();
  #pragma unroll
  for (int o = 128; o > 0; o >>= 1) {
    if (tid < o) rbuf[tid] += rbuf[tid + o];
    __syncthreads();
  }
  int sb = rbuf[0];
  int i = b * 256 + tid;
  if (i < n) { int o = ppos[i] + sb; offs[i] = o; cur[i] = o; }
  if (b == 0) {
    if (tid == 0) offs[n] = e;
    if (tid < 16) ssrc[e + tid] = 0;   // slack for deg-0 tail reads
  }
}

// ---------------- MFMA GEMM body: fp32 input rows -> bf16 h + als/ald ----------------
__device__ __forceinline__ void gemm_body(const float* __restrict__ in, const uint4* __restrict__ wf,
                                          const float* __restrict__ avs, const float* __restrict__ avd,
                                          unsigned short* __restrict__ hgb, float* __restrict__ als,
                                          float* __restrict__ ald, int n, int bid, int nbl) {
  int tid = threadIdx.x, lane = tid & 63, wv = tid >> 6;
  int l15 = lane & 15, quad = lane >> 4;
  bf16x8 bfr[4][2];
  #pragma unroll
  for (int cb = 0; cb < 8; cb++) {
    uint4 u = wf[cb * 64 + lane];
    bfr[cb >> 1][cb & 1] = *(const bf16x8*)&u;
  }
  float as_l[4], ad_l[4];
  #pragma unroll
  for (int c = 0; c < 4; c++) { as_l[c] = avs[c * 16 + l15]; ad_l[c] = avd[c * 16 + l15]; }

  int nchunks = n >> 6;
  for (int chunk = bid; chunk < nchunks; chunk += nbl) {
    int r0 = (chunk << 6) + (wv << 4);
    bf16x8 a0, a1;
    const float4* xr = (const float4*)(in + (size_t)(r0 + l15) * F + quad * 8);
    float4 xa = xr[0], xb = xr[1];
    float4 xc = xr[8], xd = xr[9];
    a0[0] = (short)f2bf(xa.x); a0[1] = (short)f2bf(xa.y); a0[2] = (short)f2bf(xa.z); a0[3] = (short)f2bf(xa.w);
    a0[4] = (short)f2bf(xb.x); a0[5] = (short)f2bf(xb.y); a0[6] = (short)f2bf(xb.z); a0[7] = (short)f2bf(xb.w);
    a1[0] = (short)f2bf(xc.x); a1[1] = (short)f2bf(xc.y); a1[2] = (short)f2bf(xc.z); a1[3] = (short)f2bf(xc.w);
    a1[4] = (short)f2bf(xd.x); a1[5] = (short)f2bf(xd.y); a1[6] = (short)f2bf(xd.z); a1[7] = (short)f2bf(xd.w);
    f32x4 cfr[4];
    #pragma unroll
    for (int c = 0; c < 4; c++) {
      cfr[c] = (f32x4){0.f, 0.f, 0.f, 0.f};
      cfr[c] = __builtin_amdgcn_mfma_f32_16x16x32_bf16(a0, bfr[c][0], cfr[c], 0, 0, 0);
      cfr[c] = __builtin_amdgcn_mfma_f32_16x16x32_bf16(a1, bfr[c][1], cfr[c], 0, 0, 0);
    }
    #pragma unroll
    for (int i = 0; i < 4; i++) {
      int row = r0 + quad * 4 + i;
      #pragma unroll
      for (int c = 0; c < 4; c++) hgb[(size_t)row * F + c * 16 + l15] = f2bf(cfr[c][i]);
      float ps = cfr[0][i] * as_l[0] + cfr[1][i] * as_l[1] + cfr[2][i] * as_l[2] + cfr[3][i] * as_l[3];
      float pd = cfr[0][i] * ad_l[0] + cfr[1][i] * ad_l[1] + cfr[2][i] * ad_l[2] + cfr[3][i] * ad_l[3];
      #pragma unroll
      for (int o = 1; o <= 8; o <<= 1) { ps += __shfl_xor(ps, o); pd += __shfl_xor(pd, o); }
      if (l15 == 0) { als[row] = ps; ald[row] = pd; }
    }
  }
}

// ---------------- pass 2 scatter (blocks < S) fused with layer-1 GEMM ----------------
__global__ __launch_bounds__(256) void k_scatter_gemm1(const int* __restrict__ esrc, const int* __restrict__ edst,
                                                       int* __restrict__ cur, int* __restrict__ ssrc,
                                                       int e, int ch, int S,
                                                       const float* __restrict__ x, const uint4* __restrict__ wf,
                                                       const float* __restrict__ avs, const float* __restrict__ avd,
                                                       unsigned short* __restrict__ hgb, float* __restrict__ als,
                                                       float* __restrict__ ald, int n) {
  int k = blockIdx.x, tid = threadIdx.x;
  if (k < S) {
    int beg = k * ch, end = min(e, beg + ch);
    int len = end - beg;
    if (len <= 0) return;
    int nv = len >> 2;
    for (int g = tid; g < nv; g += 256) {
      int i = beg + (g << 2);
      int4 d4 = *(const int4*)(edst + i);
      int4 s4 = *(const int4*)(esrc + i);
      int p0 = atomicAdd(&cur[d4.x], 1);
      int p1 = atomicAdd(&cur[d4.y], 1);
      int p2 = atomicAdd(&cur[d4.z], 1);
      int p3 = atomicAdd(&cur[d4.w], 1);
      ssrc[p0] = s4.x; ssrc[p1] = s4.y; ssrc[p2] = s4.z; ssrc[p3] = s4.w;
    }
    for (int i = beg + (nv << 2) + tid; i < end; i += 256) {
      int p = atomicAdd(&cur[edst[i]], 1);
      ssrc[p] = esrc[i];
    }
    return;
  }
  gemm_body(x, wf, avs, avd, hgb, als, ald, n, k - S, (int)gridDim.x - S);
}

// ---------------- per-node GAT aggregation (self-loop in-register) ----------------
__device__ __forceinline__ void agg_node(int node, int n, const int* __restrict__ offs,
                                         const int* __restrict__ ssrc,
                                         const uint4* __restrict__ hg4,
                                         const float* __restrict__ als,
                                         const float* __restrict__ ald,
                                         float4 bl0, float4 bl1, int l8, float r[8]) {
  int cnode = min(node, n - 1);
  int beg = offs[cnode];
  int deg = offs[cnode + 1] - beg;
  int degc = max(deg - 1, 0);
  float aldv = ald[cnode];

  // self-loop term
  float ts = als[cnode] + aldv;
  ts = fmaxf(ts, 0.2f * ts);
  float exs = __expf(ts);
  float s = exs;
  uint4 us = hg4[(size_t)cnode * 8 + l8];
  float acc[8];
  acc[0] = exs * __uint_as_float(us.x << 16);
  acc[1] = exs * __uint_as_float(us.x & 0xffff0000u);
  acc[2] = exs * __uint_as_float(us.y << 16);
  acc[3] = exs * __uint_as_float(us.y & 0xffff0000u);
  acc[4] = exs * __uint_as_float(us.z << 16);
  acc[5] = exs * __uint_as_float(us.z & 0xffff0000u);
  acc[6] = exs * __uint_as_float(us.w << 16);
  acc[7] = exs * __uint_as_float(us.w & 0xffff0000u);

  int dm = deg;
  #pragma unroll
  for (int o = 8; o <= 32; o <<= 1) dm = max(dm, __shfl_xor(dm, o));

  #pragma unroll 4
  for (int j = 0; j < dm; j++) {
    int jj = min(j, degc);
    int src = ssrc[beg + jj];
    float t = als[src] + aldv;
    t = fmaxf(t, 0.2f * t);                   // leaky_relu 0.2
    float ex = (j < deg) ? __expf(t) : 0.f;
    s += ex;
    uint4 u = hg4[(size_t)src * 8 + l8];
    acc[0] = fmaf(ex, __uint_as_float(u.x << 16), acc[0]);
    acc[1] = fmaf(ex, __uint_as_float(u.x & 0xffff0000u), acc[1]);
    acc[2] = fmaf(ex, __uint_as_float(u.y << 16), acc[2]);
    acc[3] = fmaf(ex, __uint_as_float(u.y & 0xffff0000u), acc[3]);
    acc[4] = fmaf(ex, __uint_as_float(u.z << 16), acc[4]);
    acc[5] = fmaf(ex, __uint_as_float(u.z & 0xffff0000u), acc[5]);
    acc[6] = fmaf(ex, __uint_as_float(u.w << 16), acc[6]);
    acc[7] = fmaf(ex, __uint_as_float(u.w & 0xffff0000u), acc[7]);
  }

  float iv = 1.f / (s + 1e-16f);
  r[0] = fmaxf(fmaf(acc[0], iv, bl0.x), 0.f);
  r[1] = fmaxf(fmaf(acc[1], iv, bl0.y), 0.f);
  r[2] = fmaxf(fmaf(acc[2], iv, bl0.z), 0.f);
  r[3] = fmaxf(fmaf(acc[3], iv, bl0.w), 0.f);
  r[4] = fmaxf(fmaf(acc[4], iv, bl1.x), 0.f);
  r[5] = fmaxf(fmaf(acc[5], iv, bl1.y), 0.f);
  r[6] = fmaxf(fmaf(acc[6], iv, bl1.z), 0.f);
  r[7] = fmaxf(fmaf(acc[7], iv, bl1.w), 0.f);
}

// ---------------- fused: layer-1 aggregation -> LDS tile -> layer-2 GEMM ----------------
__global__ __launch_bounds__(256) void k_spmm_g2(const int* __restrict__ offs, const int* __restrict__ ssrc,
                                                 const unsigned short* __restrict__ hgb,
                                                 const float* __restrict__ als, const float* __restrict__ ald,
                                                 const float* __restrict__ bias, const uint4* __restrict__ wf2,
                                                 const float* __restrict__ avs, const float* __restrict__ avd,
                                                 unsigned short* __restrict__ hgb2, float* __restrict__ als2,
                                                 float* __restrict__ ald2, int n) {
  __shared__ __align__(16) unsigned short hsh[64][72];  // +8 pad: balanced banks for b128 W/R
  int tid = threadIdx.x, lane = tid & 63, wv = tid >> 6;
  int g8 = lane >> 3, l8 = lane & 7;
  const uint4* hg4 = (const uint4*)hgb;
  float4 bl0 = ((const float4*)bias)[l8 * 2];
  float4 bl1 = ((const float4*)bias)[l8 * 2 + 1];

  for (int p = 0; p < 2; p++) {
    int row = p * 32 + wv * 8 + g8;
    int node = blockIdx.x * 64 + row;
    float r[8];
    agg_node(node, n, offs, ssrc, hg4, als, ald, bl0, bl1, l8, r);
    unsigned short pk[8];
    #pragma unroll
    for (int k = 0; k < 8; k++) pk[k] = f2bf(r[k]);
    *(uint4*)&hsh[row][l8 * 8] = *(const uint4*)pk;
  }
  __syncthreads();

  // layer-2 GEMM on the 64x64 LDS tile
  int l15 = lane & 15, quad = lane >> 4;
  bf16x8 bfr[4][2];
  #pragma unroll
  for (int cb = 0; cb < 8; cb++) {
    uint4 u = wf2[cb * 64 + lane];
    bfr[cb >> 1][cb & 1] = *(const bf16x8*)&u;
  }
  float as_l[4], ad_l[4];
  #pragma unroll
  for (int c = 0; c < 4; c++) { as_l[c] = avs[c * 16 + l15]; ad_l[c] = avd[c * 16 + l15]; }

  int r0 = wv << 4;
  uint4 u0 = *(const uint4*)&hsh[r0 + l15][quad * 8];
  uint4 u1 = *(const uint4*)&hsh[r0 + l15][quad * 8 + 32];
  bf16x8 a0 = *(const bf16x8*)&u0;
  bf16x8 a1 = *(const bf16x8*)&u1;
  f32x4 cfr[4];
  #pragma unroll
  for (int c = 0; c < 4; c++) {
    cfr[c] = (f32x4){0.f, 0.f, 0.f, 0.f};
    cfr[c] = __builtin_amdgcn_mfma_f32_16x16x32_bf16(a0, bfr[c][0], cfr[c], 0, 0, 0);
    cfr[c] = __builtin_amdgcn_mfma_f32_16x16x32_bf16(a1, bfr[c][1], cfr[c], 0, 0, 0);
  }
  #pragma unroll
  for (int i = 0; i < 4; i++) {
    int row = blockIdx.x * 64 + r0 + quad * 4 + i;
    #pragma unroll
    for (int c = 0; c < 4; c++) hgb2[(size_t)row * F + c * 16 + l15] = f2bf(cfr[c][i]);
    float ps = cfr[0][i] * as_l[0] + cfr[1][i] * as_l[1] + cfr[2][i] * as_l[2] + cfr[3][i] * as_l[3];
    float pd = cfr[0][i] * ad_l[0] + cfr[1][i] * ad_l[1] + cfr[2][i] * ad_l[2] + cfr[3][i] * ad_l[3];
    #pragma unroll
    for (int o = 1; o <= 8; o <<= 1) { ps += __shfl_xor(ps, o); pd += __shfl_xor(pd, o); }
    if (l15 == 0) { als2[row] = ps; ald2[row] = pd; }
  }
}

// ---------------- layer-2 aggregation + fused readout ----------------
__global__ __launch_bounds__(256) void k_spmm_out(const int* __restrict__ offs, const int* __restrict__ ssrc,
                                                  const unsigned short* __restrict__ hgb,
                                                  const float* __restrict__ als, const float* __restrict__ ald,
                                                  const float* __restrict__ bias, const float* __restrict__ Wout,
                                                  float* __restrict__ out, int n) {
  int tid = threadIdx.x, lane = tid & 63, wv = tid >> 6;
  int g8 = lane >> 3, l8 = lane & 7;
  const uint4* hg4 = (const uint4*)hgb;
  float4 bl0 = ((const float4*)bias)[l8 * 2];
  float4 bl1 = ((const float4*)bias)[l8 * 2 + 1];

  __shared__ float gsl[3];
  if (tid < 3) gsl[tid] = 0.f;

  int node = (blockIdx.x * 4 + wv) * 8 + g8;
  bool nodeok = node < n;
  int cnode = min(node, n - 1);
  float r[8];
  agg_node(node, n, offs, ssrc, hg4, als, ald, bl0, bl1, l8, r);

  int node0 = blockIdx.x * 32;
  int grp0 = node0 / 20;
  int grp = cnode / 20, slot = cnode - grp * 20;
  const float* wr = Wout + slot * F + l8 * 8;
  float dot = 0.f;
  #pragma unroll
  for (int k = 0; k < 8; k++) dot = fmaf(r[k], wr[k], dot);
  #pragma unroll
  for (int o = 1; o <= 4; o <<= 1) dot += __shfl_xor(dot, o);  // within subgroup
  __syncthreads();
  if (nodeok && l8 == 0) atomicAdd(&gsl[grp - grp0], dot);
  __syncthreads();
  if (tid < 3) {
    float v = gsl[tid];
    if (v != 0.f) atomicAdd(out + grp0 + tid, v);
  }
}

// ---------------- launch ----------------
extern "C" void kernel_launch(void* const* d_in, const int* in_sizes, int n_in,
                              void* d_out, int out_size, void* d_ws, size_t ws_size,
                              hipStream_t stream) {
  const float* x   = (const float*)d_in[0];
  const int*   ei  = (const int*)d_in[1];
  const float* W1  = (const float*)d_in[2];
  const float* as1 = (const float*)d_in[3];
  const float* ad1 = (const float*)d_in[4];
  const float* b1  = (const float*)d_in[5];
  const float* W2  = (const float*)d_in[6];
  const float* as2 = (const float*)d_in[7];
  const float* ad2 = (const float*)d_in[8];
  const float* b2  = (const float*)d_in[9];
  const float* Wo  = (const float*)d_in[10];
  const float* bo  = (const float*)d_in[11];
  float* out = (float*)d_out;

  const int N = in_sizes[0] / F;
  const int E = in_sizes[1] / 2;
  const int* esrc = ei;
  const int* edst = ei + E;

  size_t off = 0;
  auto alloc = [&](size_t bytes) -> void* {
    void* p = (char*)d_ws + off;
    off += (bytes + 255) & ~(size_t)255;
    return p;
  };
  unsigned short* hgb  = (unsigned short*)alloc((size_t)N * F * 2);  // layer-1 h (bf16)
  unsigned short* hgb2 = (unsigned short*)alloc((size_t)N * F * 2);  // layer-2 h (bf16)
  float* als  = (float*)alloc((size_t)N * 4);
  float* ald  = (float*)alloc((size_t)N * 4);
  float* als2 = (float*)alloc((size_t)N * 4);
  float* ald2 = (float*)alloc((size_t)N * 4);
  int* ndeg   = (int*)alloc((size_t)N * 4);
  int* ppos   = (int*)alloc((size_t)N * 4);
  int* cur    = (int*)alloc((size_t)N * 4);
  int* offs   = (int*)alloc((size_t)(N + 1) * 4);
  int* bsums  = (int*)alloc(4096);
  int* ssrc   = (int*)alloc((size_t)(E + 64) * 4);   // CSR src lists (no self-loops) + slack
  uint4* wf   = (uint4*)alloc(16384);                // packed W frags: 2 layers x 512 uint4
  (void)ws_size; (void)n_in; (void)out_size;

  const int NG = N / 20;
  const int gScan = (N + 255) / 256;                 // 640
  const int SC = 1024;                               // count/scatter blocks
  const int CH = (((E + SC - 1) / SC) + 3) & ~3;     // chunk, multiple of 4 for int4 loads

  k_prep<<<256, 256, 0, stream>>>(W1, W2, wf, ndeg, N, out, bo, NG);
  k_count<<<SC, 256, 0, stream>>>(edst, ndeg, E, CH);
  k_scan1<<<gScan, 256, 0, stream>>>(ndeg, ppos, bsums, N);
  k_init<<<gScan, 256, 0, stream>>>(ppos, bsums, offs, cur, ssrc, N, E);
  // fused: edge scatter (SC blocks) + layer-1 GEMM (N/64 blocks)
  k_scatter_gemm1<<<SC + (N >> 6), 256, 0, stream>>>(esrc, edst, cur, ssrc, E, CH, SC,
                                                     x, wf, as1, ad1, hgb, als, ald, N);
  // fused: layer-1 aggregation -> LDS -> layer-2 GEMM
  k_spmm_g2<<<(N >> 6), 256, 0, stream>>>(offs, ssrc, hgb, als, ald, b1, wf + 512, as2, ad2,
                                          hgb2, als2, ald2, N);
  // layer-2 aggregation + fused readout
  k_spmm_out<<<(N >> 5), 256, 0, stream>>>(offs, ssrc, hgb2, als2, ald2, b2, Wo, out, N);
}

// Round 3
// 271.214 us; speedup vs baseline: 2.0656x; 2.0656x over previous
//
#include <hip/hip_runtime.h>
#include <math.h>

#define F 64
#define NPB 160        // nodes per bucket
#define BCAP 3584      // per-bucket capacity in binned (mean 2560, +20 sigma)

typedef __attribute__((ext_vector_type(8))) short bf16x8;
typedef __attribute__((ext_vector_type(4))) float f32x4;

__device__ inline unsigned short f2bf(float f) {
  unsigned int u = __float_as_uint(f);
  u += 0x7fffu + ((u >> 16) & 1u);   // round-to-nearest-even
  return (unsigned short)(u >> 16);
}

// ---------------- prep: W fragment pack (block 0) + bcnt zero + out init ----------------
__global__ __launch_bounds__(256) void k_prep(const float* __restrict__ W1, const float* __restrict__ W2,
                                              uint4* __restrict__ wf, int* __restrict__ bcnt, int nb,
                                              float* __restrict__ out, const float* __restrict__ bo, int ng,
                                              int* __restrict__ ssrc, int e) {
  int tid = threadIdx.x;
  if (blockIdx.x == 0) {
    // pack W1/W2 into MFMA B-fragment layout: wf[layer*512 + (c*2+kk)*64 + lane] = 8 bf16 (j=0..7)
    for (int i = tid; i < 1024; i += 256) {
      int layer = i >> 9, rem = i & 511;
      int cb = rem >> 6, lane = rem & 63;
      int c = cb >> 1, kk = cb & 1;
      int l15 = lane & 15, quad = lane >> 4;
      const float* W = layer ? W2 : W1;
      unsigned short p[8];
      #pragma unroll
      for (int j = 0; j < 8; j++) {
        int kd = kk * 32 + quad * 8 + j;
        p[j] = f2bf(W[kd * F + c * 16 + l15]);
      }
      wf[i] = *(const uint4*)p;
    }
  } else {
    for (int i = tid; i < nb * 16; i += 256) bcnt[i] = 0;  // counters padded to 64B lines
    float b0 = bo[0];
    for (int i = tid; i < ng; i += 256) out[i] = b0;
    if (tid < 64) ssrc[e + tid] = 0;                       // slack
  }
}

// ---------------- MFMA GEMM body: fp32 input rows -> bf16 h + als/ald ----------------
__device__ __forceinline__ void gemm_body(const float* __restrict__ in, const uint4* __restrict__ wf,
                                          const float* __restrict__ avs, const float* __restrict__ avd,
                                          unsigned short* __restrict__ hgb, float* __restrict__ als,
                                          float* __restrict__ ald, int n, int bid, int nbl) {
  int tid = threadIdx.x, lane = tid & 63, wv = tid >> 6;
  int l15 = lane & 15, quad = lane >> 4;
  bf16x8 bfr[4][2];
  #pragma unroll
  for (int cb = 0; cb < 8; cb++) {
    uint4 u = wf[cb * 64 + lane];
    bfr[cb >> 1][cb & 1] = *(const bf16x8*)&u;
  }
  float as_l[4], ad_l[4];
  #pragma unroll
  for (int c = 0; c < 4; c++) { as_l[c] = avs[c * 16 + l15]; ad_l[c] = avd[c * 16 + l15]; }

  int nchunks = n >> 6;
  for (int chunk = bid; chunk < nchunks; chunk += nbl) {
    int r0 = (chunk << 6) + (wv << 4);
    bf16x8 a0, a1;
    const float4* xr = (const float4*)(in + (size_t)(r0 + l15) * F + quad * 8);
    float4 xa = xr[0], xb = xr[1];
    float4 xc = xr[8], xd = xr[9];
    a0[0] = (short)f2bf(xa.x); a0[1] = (short)f2bf(xa.y); a0[2] = (short)f2bf(xa.z); a0[3] = (short)f2bf(xa.w);
    a0[4] = (short)f2bf(xb.x); a0[5] = (short)f2bf(xb.y); a0[6] = (short)f2bf(xb.z); a0[7] = (short)f2bf(xb.w);
    a1[0] = (short)f2bf(xc.x); a1[1] = (short)f2bf(xc.y); a1[2] = (short)f2bf(xc.z); a1[3] = (short)f2bf(xc.w);
    a1[4] = (short)f2bf(xd.x); a1[5] = (short)f2bf(xd.y); a1[6] = (short)f2bf(xd.z); a1[7] = (short)f2bf(xd.w);
    f32x4 cfr[4];
    #pragma unroll
    for (int c = 0; c < 4; c++) {
      cfr[c] = (f32x4){0.f, 0.f, 0.f, 0.f};
      cfr[c] = __builtin_amdgcn_mfma_f32_16x16x32_bf16(a0, bfr[c][0], cfr[c], 0, 0, 0);
      cfr[c] = __builtin_amdgcn_mfma_f32_16x16x32_bf16(a1, bfr[c][1], cfr[c], 0, 0, 0);
    }
    #pragma unroll
    for (int i = 0; i < 4; i++) {
      int row = r0 + quad * 4 + i;
      #pragma unroll
      for (int c = 0; c < 4; c++) hgb[(size_t)row * F + c * 16 + l15] = f2bf(cfr[c][i]);
      float ps = cfr[0][i] * as_l[0] + cfr[1][i] * as_l[1] + cfr[2][i] * as_l[2] + cfr[3][i] * as_l[3];
      float pd = cfr[0][i] * ad_l[0] + cfr[1][i] * ad_l[1] + cfr[2][i] * ad_l[2] + cfr[3][i] * ad_l[3];
      #pragma unroll
      for (int o = 1; o <= 8; o <<= 1) { ps += __shfl_xor(ps, o); pd += __shfl_xor(pd, o); }
      if (l15 == 0) { als[row] = ps; ald[row] = pd; }
    }
  }
}

// ---------------- fused: bucketed scatter (blocks < S) + layer-1 GEMM ----------------
// Scatter block: LDS histogram of its chunk -> one global atomicAdd per (block,bucket) to
// reserve a run in binned[b*BCAP ..] -> place edges (int4 loads; chunk re-read hits L2).
__global__ __launch_bounds__(256) void k_scatter_gemm1(const int* __restrict__ esrc, const int* __restrict__ edst,
                                                       int* __restrict__ bcnt, unsigned int* __restrict__ binned,
                                                       int e, int ch, int S,
                                                       const float* __restrict__ x, const uint4* __restrict__ wf,
                                                       const float* __restrict__ avs, const float* __restrict__ avd,
                                                       unsigned short* __restrict__ hgb, float* __restrict__ als,
                                                       float* __restrict__ ald, int n) {
  int k = blockIdx.x, tid = threadIdx.x;
  if (k < S) {
    __shared__ int hist[1024];
    __shared__ int cur[1024];
    for (int i = tid; i < 1024; i += 256) hist[i] = 0;
    __syncthreads();
    int beg = k * ch, end = min(e, beg + ch);
    int len = end - beg;
    if (len <= 0) return;
    int nv = len >> 2;  // beg is 16B-aligned (ch multiple of 4)
    // phase A: histogram
    for (int g = tid; g < nv; g += 256) {
      int4 d4 = *(const int4*)(edst + beg + (g << 2));
      atomicAdd(&hist[d4.x / NPB], 1);
      atomicAdd(&hist[d4.y / NPB], 1);
      atomicAdd(&hist[d4.z / NPB], 1);
      atomicAdd(&hist[d4.w / NPB], 1);
    }
    for (int i = beg + (nv << 2) + tid; i < end; i += 256) atomicAdd(&hist[edst[i] / NPB], 1);
    __syncthreads();
    // phase B: reserve per-bucket runs (global atomics on padded counters)
    for (int b = tid; b < 1024; b += 256) {
      int c = hist[b];
      int base = 0;
      if (c) base = atomicAdd(&bcnt[b * 16], c);
      cur[b] = b * BCAP + base;
    }
    __syncthreads();
    // phase C: place
    for (int g = tid; g < nv; g += 256) {
      int i = beg + (g << 2);
      int4 d4 = *(const int4*)(edst + i);
      int4 s4 = *(const int4*)(esrc + i);
      #pragma unroll
      for (int j = 0; j < 4; j++) {
        int d = (j == 0) ? d4.x : (j == 1) ? d4.y : (j == 2) ? d4.z : d4.w;
        int s = (j == 0) ? s4.x : (j == 1) ? s4.y : (j == 2) ? s4.z : s4.w;
        int b = d / NPB;
        int p = atomicAdd(&cur[b], 1);
        if (p < (b + 1) * BCAP) binned[p] = (unsigned int)s | ((unsigned int)(d - b * NPB) << 24);
      }
    }
    for (int i = beg + (nv << 2) + tid; i < end; i += 256) {
      int d = edst[i];
      int b = d / NPB;
      int p = atomicAdd(&cur[b], 1);
      if (p < (b + 1) * BCAP) binned[p] = (unsigned int)esrc[i] | ((unsigned int)(d - b * NPB) << 24);
    }
    return;
  }
  gemm_body(x, wf, avs, avd, hgb, als, ald, n, k - S, (int)gridDim.x - S);
}

// one block per bucket: prefix obase from bcnt (L2-resident), per-node counting sort via
// LDS stage, emit packed ssrc + offs. Edges only (self-loops handled in-register downstream).
__global__ __launch_bounds__(256) void k_bucket_csr(const unsigned int* __restrict__ binned,
                                                    const int* __restrict__ bcnt,
                                                    int* __restrict__ ssrc, int* __restrict__ offs,
                                                    int n, int nb) {
  __shared__ int ncnt[NPB];
  __shared__ int cur[NPB];
  __shared__ int sc[256];
  __shared__ int red[256];
  __shared__ int stage[BCAP];
  int b = blockIdx.x, tid = threadIdx.x;
  // output base: prefix sum over earlier buckets (bcnt is 64KB, L2-resident)
  int acc = 0;
  for (int j = tid; j < b; j += 256) acc += min(bcnt[j * 16], BCAP);
  red[tid] = acc;
  __syncthreads();
  #pragma unroll
  for (int o = 128; o > 0; o >>= 1) {
    if (tid < o) red[tid] += red[tid + o];
    __syncthreads();
  }
  int outbase = red[0];
  int ecnt = min(bcnt[b * 16], BCAP);
  int node0 = b * NPB;
  int nn = min(NPB, n - node0);
  int ebeg = b * BCAP;
  for (int i = tid; i < NPB; i += 256) ncnt[i] = 0;
  __syncthreads();
  for (int i = tid; i < ecnt; i += 256) { unsigned int v = binned[ebeg + i]; atomicAdd(&ncnt[v >> 24], 1); }
  __syncthreads();
  int x = (tid < nn) ? ncnt[tid] : 0;
  sc[tid] = x;
  __syncthreads();
  #pragma unroll
  for (int o = 1; o < 256; o <<= 1) {
    int y = (tid >= o) ? sc[tid - o] : 0;
    __syncthreads();
    sc[tid] += y;
    __syncthreads();
  }
  if (tid < nn) {
    int noff = sc[tid] - x;
    cur[tid] = noff;
    offs[node0 + tid] = outbase + noff;
  }
  __syncthreads();
  for (int i = tid; i < ecnt; i += 256) {
    unsigned int v = binned[ebeg + i];
    int p = atomicAdd(&cur[v >> 24], 1);
    stage[p] = (int)(v & 0xFFFFFFu);
  }
  __syncthreads();
  for (int i = tid; i < ecnt; i += 256) ssrc[outbase + i] = stage[i];
  if (b == nb - 1 && tid == 0) offs[n] = outbase + ecnt;
}

// ---------------- per-node GAT aggregation (self-loop in-register) ----------------
__device__ __forceinline__ void agg_node(int node, int n, const int* __restrict__ offs,
                                         const int* __restrict__ ssrc,
                                         const uint4* __restrict__ hg4,
                                         const float* __restrict__ als,
                                         const float* __restrict__ ald,
                                         float4 bl0, float4 bl1, int l8, float r[8]) {
  int cnode = min(node, n - 1);
  int beg = offs[cnode];
  int deg = offs[cnode + 1] - beg;
  int degc = max(deg - 1, 0);
  if (deg == 0) beg = 0;          // safe dummy reads (ex=0 masks them)
  float aldv = ald[cnode];

  // self-loop term
  float ts = als[cnode] + aldv;
  ts = fmaxf(ts, 0.2f * ts);
  float exs = __expf(ts);
  float s = exs;
  uint4 us = hg4[(size_t)cnode * 8 + l8];
  float acc[8];
  acc[0] = exs * __uint_as_float(us.x << 16);
  acc[1] = exs * __uint_as_float(us.x & 0xffff0000u);
  acc[2] = exs * __uint_as_float(us.y << 16);
  acc[3] = exs * __uint_as_float(us.y & 0xffff0000u);
  acc[4] = exs * __uint_as_float(us.z << 16);
  acc[5] = exs * __uint_as_float(us.z & 0xffff0000u);
  acc[6] = exs * __uint_as_float(us.w << 16);
  acc[7] = exs * __uint_as_float(us.w & 0xffff0000u);

  int dm = deg;
  #pragma unroll
  for (int o = 8; o <= 32; o <<= 1) dm = max(dm, __shfl_xor(dm, o));

  #pragma unroll 4
  for (int j = 0; j < dm; j++) {
    int jj = min(j, degc);
    int src = ssrc[beg + jj];
    float t = als[src] + aldv;
    t = fmaxf(t, 0.2f * t);                   // leaky_relu 0.2
    float ex = (j < deg) ? __expf(t) : 0.f;
    s += ex;
    uint4 u = hg4[(size_t)src * 8 + l8];
    acc[0] = fmaf(ex, __uint_as_float(u.x << 16), acc[0]);
    acc[1] = fmaf(ex, __uint_as_float(u.x & 0xffff0000u), acc[1]);
    acc[2] = fmaf(ex, __uint_as_float(u.y << 16), acc[2]);
    acc[3] = fmaf(ex, __uint_as_float(u.y & 0xffff0000u), acc[3]);
    acc[4] = fmaf(ex, __uint_as_float(u.z << 16), acc[4]);
    acc[5] = fmaf(ex, __uint_as_float(u.z & 0xffff0000u), acc[5]);
    acc[6] = fmaf(ex, __uint_as_float(u.w << 16), acc[6]);
    acc[7] = fmaf(ex, __uint_as_float(u.w & 0xffff0000u), acc[7]);
  }

  float iv = 1.f / (s + 1e-16f);
  r[0] = fmaxf(fmaf(acc[0], iv, bl0.x), 0.f);
  r[1] = fmaxf(fmaf(acc[1], iv, bl0.y), 0.f);
  r[2] = fmaxf(fmaf(acc[2], iv, bl0.z), 0.f);
  r[3] = fmaxf(fmaf(acc[3], iv, bl0.w), 0.f);
  r[4] = fmaxf(fmaf(acc[4], iv, bl1.x), 0.f);
  r[5] = fmaxf(fmaf(acc[5], iv, bl1.y), 0.f);
  r[6] = fmaxf(fmaf(acc[6], iv, bl1.z), 0.f);
  r[7] = fmaxf(fmaf(acc[7], iv, bl1.w), 0.f);
}

// ---------------- fused: layer-1 aggregation -> LDS tile -> layer-2 GEMM ----------------
__global__ __launch_bounds__(256) void k_spmm_g2(const int* __restrict__ offs, const int* __restrict__ ssrc,
                                                 const unsigned short* __restrict__ hgb,
                                                 const float* __restrict__ als, const float* __restrict__ ald,
                                                 const float* __restrict__ bias, const uint4* __restrict__ wf2,
                                                 const float* __restrict__ avs, const float* __restrict__ avd,
                                                 unsigned short* __restrict__ hgb2, float* __restrict__ als2,
                                                 float* __restrict__ ald2, int n) {
  __shared__ __align__(16) unsigned short hsh[64][72];  // +8 pad: balanced banks for b128 W/R
  int tid = threadIdx.x, lane = tid & 63, wv = tid >> 6;
  int g8 = lane >> 3, l8 = lane & 7;
  const uint4* hg4 = (const uint4*)hgb;
  float4 bl0 = ((const float4*)bias)[l8 * 2];
  float4 bl1 = ((const float4*)bias)[l8 * 2 + 1];

  for (int p = 0; p < 2; p++) {
    int row = p * 32 + wv * 8 + g8;
    int node = blockIdx.x * 64 + row;
    float r[8];
    agg_node(node, n, offs, ssrc, hg4, als, ald, bl0, bl1, l8, r);
    unsigned short pk[8];
    #pragma unroll
    for (int k = 0; k < 8; k++) pk[k] = f2bf(r[k]);
    *(uint4*)&hsh[row][l8 * 8] = *(const uint4*)pk;
  }
  __syncthreads();

  // layer-2 GEMM on the 64x64 LDS tile
  int l15 = lane & 15, quad = lane >> 4;
  bf16x8 bfr[4][2];
  #pragma unroll
  for (int cb = 0; cb < 8; cb++) {
    uint4 u = wf2[cb * 64 + lane];
    bfr[cb >> 1][cb & 1] = *(const bf16x8*)&u;
  }
  float as_l[4], ad_l[4];
  #pragma unroll
  for (int c = 0; c < 4; c++) { as_l[c] = avs[c * 16 + l15]; ad_l[c] = avd[c * 16 + l15]; }

  int r0 = wv << 4;
  uint4 u0 = *(const uint4*)&hsh[r0 + l15][quad * 8];
  uint4 u1 = *(const uint4*)&hsh[r0 + l15][quad * 8 + 32];
  bf16x8 a0 = *(const bf16x8*)&u0;
  bf16x8 a1 = *(const bf16x8*)&u1;
  f32x4 cfr[4];
  #pragma unroll
  for (int c = 0; c < 4; c++) {
    cfr[c] = (f32x4){0.f, 0.f, 0.f, 0.f};
    cfr[c] = __builtin_amdgcn_mfma_f32_16x16x32_bf16(a0, bfr[c][0], cfr[c], 0, 0, 0);
    cfr[c] = __builtin_amdgcn_mfma_f32_16x16x32_bf16(a1, bfr[c][1], cfr[c], 0, 0, 0);
  }
  #pragma unroll
  for (int i = 0; i < 4; i++) {
    int row = blockIdx.x * 64 + r0 + quad * 4 + i;
    #pragma unroll
    for (int c = 0; c < 4; c++) hgb2[(size_t)row * F + c * 16 + l15] = f2bf(cfr[c][i]);
    float ps = cfr[0][i] * as_l[0] + cfr[1][i] * as_l[1] + cfr[2][i] * as_l[2] + cfr[3][i] * as_l[3];
    float pd = cfr[0][i] * ad_l[0] + cfr[1][i] * ad_l[1] + cfr[2][i] * ad_l[2] + cfr[3][i] * ad_l[3];
    #pragma unroll
    for (int o = 1; o <= 8; o <<= 1) { ps += __shfl_xor(ps, o); pd += __shfl_xor(pd, o); }
    if (l15 == 0) { als2[row] = ps; ald2[row] = pd; }
  }
}

// ---------------- layer-2 aggregation + fused readout ----------------
__global__ __launch_bounds__(256) void k_spmm_out(const int* __restrict__ offs, const int* __restrict__ ssrc,
                                                  const unsigned short* __restrict__ hgb,
                                                  const float* __restrict__ als, const float* __restrict__ ald,
                                                  const float* __restrict__ bias, const float* __restrict__ Wout,
                                                  float* __restrict__ out, int n) {
  int tid = threadIdx.x, lane = tid & 63, wv = tid >> 6;
  int g8 = lane >> 3, l8 = lane & 7;
  const uint4* hg4 = (const uint4*)hgb;
  float4 bl0 = ((const float4*)bias)[l8 * 2];
  float4 bl1 = ((const float4*)bias)[l8 * 2 + 1];

  __shared__ float gsl[3];
  if (tid < 3) gsl[tid] = 0.f;

  int node = (blockIdx.x * 4 + wv) * 8 + g8;
  bool nodeok = node < n;
  int cnode = min(node, n - 1);
  float r[8];
  agg_node(node, n, offs, ssrc, hg4, als, ald, bl0, bl1, l8, r);

  int node0 = blockIdx.x * 32;
  int grp0 = node0 / 20;
  int grp = cnode / 20, slot = cnode - grp * 20;
  const float* wr = Wout + slot * F + l8 * 8;
  float dot = 0.f;
  #pragma unroll
  for (int k = 0; k < 8; k++) dot = fmaf(r[k], wr[k], dot);
  #pragma unroll
  for (int o = 1; o <= 4; o <<= 1) dot += __shfl_xor(dot, o);  // within subgroup
  __syncthreads();
  if (nodeok && l8 == 0) atomicAdd(&gsl[grp - grp0], dot);
  __syncthreads();
  if (tid < 3) {
    float v = gsl[tid];
    if (v != 0.f) atomicAdd(out + grp0 + tid, v);
  }
}

// ---------------- launch ----------------
extern "C" void kernel_launch(void* const* d_in, const int* in_sizes, int n_in,
                              void* d_out, int out_size, void* d_ws, size_t ws_size,
                              hipStream_t stream) {
  const float* x   = (const float*)d_in[0];
  const int*   ei  = (const int*)d_in[1];
  const float* W1  = (const float*)d_in[2];
  const float* as1 = (const float*)d_in[3];
  const float* ad1 = (const float*)d_in[4];
  const float* b1  = (const float*)d_in[5];
  const float* W2  = (const float*)d_in[6];
  const float* as2 = (const float*)d_in[7];
  const float* ad2 = (const float*)d_in[8];
  const float* b2  = (const float*)d_in[9];
  const float* Wo  = (const float*)d_in[10];
  const float* bo  = (const float*)d_in[11];
  float* out = (float*)d_out;

  const int N = in_sizes[0] / F;
  const int E = in_sizes[1] / 2;
  const int* esrc = ei;
  const int* edst = ei + E;

  size_t off = 0;
  auto alloc = [&](size_t bytes) -> void* {
    void* p = (char*)d_ws + off;
    off += (bytes + 255) & ~(size_t)255;
    return p;
  };
  unsigned short* hgb  = (unsigned short*)alloc((size_t)N * F * 2);  // layer-1 h (bf16)
  unsigned short* hgb2 = (unsigned short*)alloc((size_t)N * F * 2);  // layer-2 h (bf16)
  float* als  = (float*)alloc((size_t)N * 4);
  float* ald  = (float*)alloc((size_t)N * 4);
  float* als2 = (float*)alloc((size_t)N * 4);
  float* ald2 = (float*)alloc((size_t)N * 4);
  int* offs   = (int*)alloc((size_t)(N + 1) * 4);
  int* bcnt   = (int*)alloc((size_t)1024 * 16 * 4);  // per-bucket counters, 64B-padded
  int* ssrc   = (int*)alloc((size_t)(E + 64) * 4);   // CSR src lists (edges only) + slack
  unsigned int* binned = (unsigned int*)alloc((size_t)1024 * BCAP * 4);
  uint4* wf   = (uint4*)alloc(16384);                // packed W frags: 2 layers x 512 uint4
  (void)ws_size; (void)n_in; (void)out_size;

  const int NG = N / 20;
  const int NB = (N + NPB - 1) / NPB;                // 1024
  const int S = 256;                                 // scatter blocks
  const int CH = (((E + S - 1) / S) + 3) & ~3;       // chunk, multiple of 4 for int4 loads

  // W pack + counter zero + out init + ssrc slack
  k_prep<<<2, 256, 0, stream>>>(W1, W2, wf, bcnt, NB, out, bo, NG, ssrc, E);
  // fused: bucketed scatter (S blocks) + layer-1 GEMM (N/64 blocks)
  k_scatter_gemm1<<<S + (N >> 6), 256, 0, stream>>>(esrc, edst, bcnt, binned, E, CH, S,
                                                    x, wf, as1, ad1, hgb, als, ald, N);
  // per-bucket CSR build (obase computed in-kernel from bcnt)
  k_bucket_csr<<<NB, 256, 0, stream>>>(binned, bcnt, ssrc, offs, N, NB);
  // fused: layer-1 aggregation -> LDS -> layer-2 GEMM
  k_spmm_g2<<<(N >> 6), 256, 0, stream>>>(offs, ssrc, hgb, als, ald, b1, wf + 512, as2, ad2,
                                          hgb2, als2, ald2, N);
  // layer-2 aggregation + fused readout
  k_spmm_out<<<(N >> 5), 256, 0, stream>>>(offs, ssrc, hgb2, als2, ald2, b2, Wo, out, N);
}